// Round 1
// baseline (276.772 us; speedup 1.0000x reference)
//
#include <hip/hip_runtime.h>
#include <stdint.h>

// MissModel: out = chain of 20 x Linear(64,64) over 524288 tokens (fp32 io).
// Strategy: y^T = W h^T with 16x16x32 bf16 MFMA; token index stays in lane&15
// (C col) across all layers. Weight rows are pre-permuted so that layer l's
// C/D register layout IS layer l+1's B-operand layout -> inter-layer
// transform = 32 bf16 packs per wave-layer, nothing else.

using short8  = __attribute__((ext_vector_type(8))) short;  // 8 bf16 (4 VGPRs)
using floatx4 = __attribute__((ext_vector_type(4))) float;  // MFMA 16x16 acc

#define N_TOK   524288
#define N_LAYER 20

// round-half-up float->bf16 pair pack (<= half-ulp error, 3-4 VALU)
__device__ __forceinline__ uint32_t pk_bf16(float lo, float hi) {
  uint32_t a = __float_as_uint(lo) + 0x8000u;
  uint32_t b = __float_as_uint(hi) + 0x8000u;
  return (b & 0xffff0000u) | (a >> 16);
}

// exact RNE for the one-time weight conversion
__device__ __forceinline__ uint16_t bf16_rne(float f) {
  uint32_t u = __float_as_uint(f);
  u += 0x7fffu + ((u >> 16) & 1u);
  return (uint16_t)(u >> 16);
}

// ---------------------------------------------------------------------------
// Pre-permute W (fp32 [20][64][64], W[l][j][k]) into bf16 A-fragments.
// A-frag (mt,ks): lane holds A[m=lane&15][k = 32*ks + 8*(lane>>4) + j], j=0..7.
// Row m of C-tile mt carries OUTPUT feature
//   F(mt,m) = 32*(mt>>1) + 8*(m>>2) + 4*(mt&1) + (m&3)
// chosen so that C/D regs land exactly where the next layer's B-frags want
// them (k = 32*ks' + 8*quad + j per lane).
// ws layout: [l][frag = mt*2+ks][lane] -> 16 B each (j contiguous).
// ---------------------------------------------------------------------------
__global__ void prep_weights(const float* __restrict__ W, uint16_t* __restrict__ ws) {
  int idx  = blockIdx.x * 256 + threadIdx.x;   // [0, 10240)
  int l    = idx >> 9;                         // / (8 frags * 64 lanes)
  int rem  = idx & 511;
  int frag = rem >> 6;
  int lane = rem & 63;
  int mt = frag >> 1, ks = frag & 1;
  int m  = lane & 15;
  int q  = lane >> 4;
  int wrow = 32 * (mt >> 1) + 8 * (m >> 2) + 4 * (mt & 1) + (m & 3);
  int k0   = 32 * ks + 8 * q;
  const float* src = W + l * 4096 + wrow * 64 + k0;
  float4 f0 = *(const float4*)(src);
  float4 f1 = *(const float4*)(src + 4);
  union { uint16_t s[8]; uint4 v; } o;
  o.s[0] = bf16_rne(f0.x); o.s[1] = bf16_rne(f0.y);
  o.s[2] = bf16_rne(f0.z); o.s[3] = bf16_rne(f0.w);
  o.s[4] = bf16_rne(f1.x); o.s[5] = bf16_rne(f1.y);
  o.s[6] = bf16_rne(f1.z); o.s[7] = bf16_rne(f1.w);
  *(uint4*)(ws + (size_t)idx * 8) = o.v;
}

union BFrag { short8 v; uint32_t u[4]; };

// ---------------------------------------------------------------------------
// Fused 20-layer chain. 256 threads = 4 independent waves, 64 tokens/wave.
// Per wave: acc[tb=4][mt=4] floatx4 (64 VGPRs), Bf[tb=4][ks=2] (32 VGPRs),
// Af[8] (32 VGPRs). Weights double-buffered through LDS (8 KB/layer),
// register-prefetched one layer ahead; one barrier per layer.
// ---------------------------------------------------------------------------
__global__ __launch_bounds__(256, 2) void chain_fused(
    const float* __restrict__ x, const uint16_t* __restrict__ wf,
    const float* __restrict__ bias, float* __restrict__ out)
{
  __shared__ uint4 wbuf[2][512];                 // 2 x 8 KB: one layer's 8 A-frags
  __shared__ __align__(16) float biasLds[N_LAYER * 64];

  const int tid  = threadIdx.x;
  const int wv   = tid >> 6;
  const int lane = tid & 63;
  const int tl   = lane & 15;                    // token within 16-block (C col)
  const int q    = lane >> 4;                    // quad
  const int tokbase = blockIdx.x * 256 + wv * 64;

  // stage all biases (5 KB) once
  for (int i = tid; i < N_LAYER * 64; i += 256) biasLds[i] = bias[i];

  // stage layer-0 fragments
  {
    const uint4* s = (const uint4*)wf + tid * 2;
    wbuf[0][tid * 2]     = s[0];
    wbuf[0][tid * 2 + 1] = s[1];
  }

  // load x -> initial B-frags: lane needs x[tok][32*ks + 8*q + 0..7]
  BFrag Bf[4][2];
  #pragma unroll
  for (int tb = 0; tb < 4; tb++) {
    const float* xp = x + (size_t)(tokbase + tb * 16 + tl) * 64 + 8 * q;
    #pragma unroll
    for (int ks = 0; ks < 2; ks++) {
      float4 a0 = *(const float4*)(xp + 32 * ks);
      float4 a1 = *(const float4*)(xp + 32 * ks + 4);
      Bf[tb][ks].u[0] = pk_bf16(a0.x, a0.y);
      Bf[tb][ks].u[1] = pk_bf16(a0.z, a0.w);
      Bf[tb][ks].u[2] = pk_bf16(a1.x, a1.y);
      Bf[tb][ks].u[3] = pk_bf16(a1.z, a1.w);
    }
  }
  __syncthreads();

  floatx4 acc[4][4];
  int cur = 0;
  #pragma unroll 2
  for (int l = 0; l < N_LAYER; l++) {
    // prefetch next layer's fragments into registers (L2-resident, 32 B/thread)
    uint4 pv0, pv1;
    if (l + 1 < N_LAYER) {
      const uint4* s = (const uint4*)wf + (size_t)(l + 1) * 512 + tid * 2;
      pv0 = s[0]; pv1 = s[1];
    }

    // A-frags from LDS (broadcast across the block's 4 waves)
    short8 Af[8];
    const short8* ap = (const short8*)&wbuf[cur][0];
    #pragma unroll
    for (int f = 0; f < 8; f++) Af[f] = ap[f * 64 + lane];

    // acc init = bias at the permuted feature positions:
    // acc[tb][mt][e] must hold b[l][32*(mt>>1) + 8*q + 4*(mt&1) + e]
    #pragma unroll
    for (int mt = 0; mt < 4; mt++) {
      floatx4 bv = *(const floatx4*)(biasLds + l * 64 + 32 * (mt >> 1) + 4 * (mt & 1) + 8 * q);
      #pragma unroll
      for (int tb = 0; tb < 4; tb++) acc[tb][mt] = bv;
    }

    // 32 MFMAs: 16 independent dep-chains of length 2
    #pragma unroll
    for (int ks = 0; ks < 2; ks++)
      #pragma unroll
      for (int mt = 0; mt < 4; mt++)
        #pragma unroll
        for (int tb = 0; tb < 4; tb++)
          acc[tb][mt] = __builtin_amdgcn_mfma_f32_16x16x32_bf16(
              Af[mt * 2 + ks], Bf[tb][ks].v, acc[tb][mt], 0, 0, 0);

    if (l == N_LAYER - 1) break;

    // C/D -> next-layer B-frags: pure per-lane repack (permutation did the rest)
    #pragma unroll
    for (int tb = 0; tb < 4; tb++)
      #pragma unroll
      for (int mt = 0; mt < 4; mt++) {
        const int ksn = mt >> 1;
        const int d   = 2 * (mt & 1);
        Bf[tb][ksn].u[d]     = pk_bf16(acc[tb][mt][0], acc[tb][mt][1]);
        Bf[tb][ksn].u[d + 1] = pk_bf16(acc[tb][mt][2], acc[tb][mt][3]);
      }

    // commit prefetched weights to the other LDS buffer
    wbuf[cur ^ 1][tid * 2]     = pv0;
    wbuf[cur ^ 1][tid * 2 + 1] = pv1;
    __syncthreads();
    cur ^= 1;
  }

  // store: acc[tb][mt] = out[tok][32*(mt>>1) + 8*q + 4*(mt&1) + 0..3]
  #pragma unroll
  for (int tb = 0; tb < 4; tb++) {
    float* op = out + (size_t)(tokbase + tb * 16 + tl) * 64;
    #pragma unroll
    for (int mt = 0; mt < 4; mt++)
      *(floatx4*)(op + 32 * (mt >> 1) + 4 * (mt & 1) + 8 * q) = acc[tb][mt];
  }
}

extern "C" void kernel_launch(void* const* d_in, const int* in_sizes, int n_in,
                              void* d_out, int out_size, void* d_ws, size_t ws_size,
                              hipStream_t stream) {
  (void)in_sizes; (void)n_in; (void)out_size; (void)ws_size;
  const float* x = (const float*)d_in[0];
  const float* W = (const float*)d_in[1];   // [20][64][64] fp32
  const float* b = (const float*)d_in[2];   // [20][64] fp32
  float* out = (float*)d_out;
  uint16_t* ws = (uint16_t*)d_ws;           // needs 160 KB for bf16 frags

  prep_weights<<<dim3(40), dim3(256), 0, stream>>>(W, ws);
  chain_fused<<<dim3(N_TOK / 256), dim3(256), 0, stream>>>(x, ws, b, out);
}